// Round 1
// baseline (391.282 us; speedup 1.0000x reference)
//
#include <hip/hip_runtime.h>

#define N_ELEM 4096
#define BLOCK 256
#define PER 16            // N_ELEM / BLOCK
#define NITER 40
#define CAPACITY 600.0f
#define DAMPING 1e-3f

// ~0.5-ulp reciprocal: v_rcp_f32 + one Newton-Raphson refinement (2 FMAs).
__device__ __forceinline__ float fast_rcp(float a) {
    float r = __builtin_amdgcn_rcpf(a);
    r = fmaf(r, fmaf(-a, r, 1.0f), r);
    return r;
}

// Fused 3-value block sum-reduction; result broadcast to all threads.
// lds must hold >= 12 floats. Block = 256 threads = 4 waves.
__device__ __forceinline__ void block_reduce3(float& a, float& b, float& c, float* lds) {
    #pragma unroll
    for (int off = 32; off > 0; off >>= 1) {
        a += __shfl_down(a, off, 64);
        b += __shfl_down(b, off, 64);
        c += __shfl_down(c, off, 64);
    }
    const int wave = threadIdx.x >> 6;
    if ((threadIdx.x & 63) == 0) {
        lds[wave * 3 + 0] = a;
        lds[wave * 3 + 1] = b;
        lds[wave * 3 + 2] = c;
    }
    __syncthreads();
    a = (lds[0] + lds[3]) + (lds[6] + lds[9]);
    b = (lds[1] + lds[4]) + (lds[7] + lds[10]);
    c = (lds[2] + lds[5]) + (lds[8] + lds[11]);
    __syncthreads();   // protect lds reuse
}

// Block min-reduction; result broadcast to all threads. lds >= 4 floats.
__device__ __forceinline__ float block_reduce_min(float v, float* lds) {
    #pragma unroll
    for (int off = 32; off > 0; off >>= 1) {
        v = fminf(v, __shfl_down(v, off, 64));
    }
    const int wave = threadIdx.x >> 6;
    if ((threadIdx.x & 63) == 0) lds[wave] = v;
    __syncthreads();
    v = fminf(fminf(lds[0], lds[1]), fminf(lds[2], lds[3]));
    __syncthreads();
    return v;
}

__global__ __launch_bounds__(BLOCK) void ipm_knapsack_kernel(
        const float* __restrict__ costs,
        const float* __restrict__ weights,
        float* __restrict__ out) {
    __shared__ float lds[12];
    const int row = blockIdx.x;
    const int t   = threadIdx.x;

    float c[PER], w[PER], x[PER], F1[PER], iH[PER];

    // Coalesced float4 loads: thread t owns flat elements {4*(t+256k)+j}.
    const float4* c4 = reinterpret_cast<const float4*>(costs + (size_t)row * N_ELEM);
    const float4* w4 = reinterpret_cast<const float4*>(weights);
    #pragma unroll
    for (int k = 0; k < 4; ++k) {
        float4 cc = c4[t + 256 * k];
        float4 ww = w4[t + 256 * k];
        c[4 * k + 0] = -cc.x; c[4 * k + 1] = -cc.y; c[4 * k + 2] = -cc.z; c[4 * k + 3] = -cc.w;
        w[4 * k + 0] =  ww.x; w[4 * k + 1] =  ww.y; w[4 * k + 2] =  ww.z; w[4 * k + 3] =  ww.w;
    }

    // x0 = capacity / sum(weights)
    float ws = 0.0f, z1 = 0.0f, z2 = 0.0f;
    #pragma unroll
    for (int k = 0; k < PER; ++k) ws += w[k];
    block_reduce3(ws, z1, z2, lds);
    const float x0 = CAPACITY / ws;
    #pragma unroll
    for (int k = 0; k < PER; ++k) x[k] = x0;
    float lam = 0.0f;

    for (int it = 0; it <= NITER; ++it) {
        // mu = max(2^-it, damping); 2^-it exact via exponent-bit construction.
        const float mu = (it < 10) ? __uint_as_float((unsigned)(127 - it) << 23) : DAMPING;

        // ---- Phase A: residuals, diag Hessian, 3 row-sums ----
        float s1 = 0.0f, s2 = 0.0f, s3 = 0.0f;
        #pragma unroll
        for (int k = 0; k < PER; ++k) {
            const float xk = x[k], wk = w[k];
            const float p    = 1.0f - xk;
            const float u    = xk * p;                    // x(1-x)
            const float tinv = fast_rcp(u);               // 1/(x(1-x))
            const float q    = 2.0f * xk - 1.0f;
            // F1 = c + lam*w + mu*(1/(1-x) - 1/x) = c + lam*w + mu*(2x-1)/u
            const float f1   = fmaf(mu * q, tinv, fmaf(lam, wk, c[k]));
            const float ssq  = fmaf(xk, xk, p * p);       // x^2 + (1-x)^2
            const float H    = mu * ssq * tinv * tinv;    // mu*(1/x^2 + 1/(1-x)^2)
            const float ih   = fast_rcp(H);
            const float wih  = wk * ih;                   // w / H
            s1 = fmaf(wih, f1, s1);
            s2 = fmaf(wih, wk, s2);
            s3 = fmaf(xk, wk, s3);
            F1[k] = f1;
            iH[k] = ih;
        }
        block_reduce3(s1, s2, s3, lds);
        const float dlam = ((s3 - CAPACITY) - s1) / s2;   // scalar Schur

        if (it == NITER) {
            // ---- KKT refine at mu = damping: out = x + dx (full step) ----
            float4* o4 = reinterpret_cast<float4*>(out + (size_t)row * N_ELEM);
            #pragma unroll
            for (int k = 0; k < 4; ++k) {
                float4 v;
                v.x = x[4*k+0] - fmaf(dlam, w[4*k+0], F1[4*k+0]) * iH[4*k+0];
                v.y = x[4*k+1] - fmaf(dlam, w[4*k+1], F1[4*k+1]) * iH[4*k+1];
                v.z = x[4*k+2] - fmaf(dlam, w[4*k+2], F1[4*k+2]) * iH[4*k+2];
                v.w = x[4*k+3] - fmaf(dlam, w[4*k+3], F1[4*k+3]) * iH[4*k+3];
                o4[t + 256 * k] = v;
            }
            return;
        }

        // ---- Phase B: fraction-to-boundary step length ----
        float tmin = __builtin_inff();
        #pragma unroll
        for (int k = 0; k < PER; ++k) {
            const float dx = -(fmaf(dlam, w[k], F1[k]) * iH[k]);
            const float r  = __builtin_amdgcn_rcpf(dx);   // raw rcp: no NaN for dx=0 path (guarded)
            const float tc = (dx > 0.0f) ? (1.0f - x[k]) * r
                           : ((dx < 0.0f) ? (-x[k]) * r : __builtin_inff());
            tmin = fminf(tmin, tc);
        }
        tmin = block_reduce_min(tmin, lds);
        const float alpha = fminf(1.0f, 0.99f * tmin);

        #pragma unroll
        for (int k = 0; k < PER; ++k) {
            const float dx = -(fmaf(dlam, w[k], F1[k]) * iH[k]);
            x[k] = fmaf(alpha, dx, x[k]);
        }
        lam = fmaf(alpha, dlam, lam);
    }
}

extern "C" void kernel_launch(void* const* d_in, const int* in_sizes, int n_in,
                              void* d_out, int out_size, void* d_ws, size_t ws_size,
                              hipStream_t stream) {
    const float* costs   = (const float*)d_in[0];
    const float* weights = (const float*)d_in[1];
    float* out = (float*)d_out;
    const int B = in_sizes[0] / N_ELEM;   // 2048 rows
    ipm_knapsack_kernel<<<B, BLOCK, 0, stream>>>(costs, weights, out);
}

// Round 2
// 301.983 us; speedup vs baseline: 1.2957x; 1.2957x over previous
//
#include <hip/hip_runtime.h>

#define N_ELEM 4096
#define BLOCK 256
#define PER 16            // N_ELEM / BLOCK
#define NITER 40
#define CAPACITY 600.0f
#define DAMPING 1e-3f

// Raw v_rcp_f32 (~1 ulp). The Newton iteration is self-correcting and the
// tolerance is 2e-2 absmax, so no NR refinement needed anywhere.
__device__ __forceinline__ float raw_rcp(float a) { return __builtin_amdgcn_rcpf(a); }

// Fused 2-value block sum-reduction (butterfly), result broadcast. 4 waves.
__device__ __forceinline__ void block_reduce2(float& a, float& b, float* lds) {
    #pragma unroll
    for (int off = 32; off > 0; off >>= 1) {
        a += __shfl_xor(a, off, 64);
        b += __shfl_xor(b, off, 64);
    }
    const int wave = threadIdx.x >> 6;
    if ((threadIdx.x & 63) == 0) { lds[wave * 2 + 0] = a; lds[wave * 2 + 1] = b; }
    __syncthreads();
    a = (lds[0] + lds[2]) + (lds[4] + lds[6]);
    b = (lds[1] + lds[3]) + (lds[5] + lds[7]);
    __syncthreads();
}

__device__ __forceinline__ float block_reduce_max(float v, float* lds) {
    #pragma unroll
    for (int off = 32; off > 0; off >>= 1) v = fmaxf(v, __shfl_xor(v, off, 64));
    const int wave = threadIdx.x >> 6;
    if ((threadIdx.x & 63) == 0) lds[wave] = v;
    __syncthreads();
    v = fmaxf(fmaxf(lds[0], lds[1]), fmaxf(lds[2], lds[3]));
    __syncthreads();
    return v;
}

// launch_bounds(256,3): cap ~168 arch VGPRs so the 6x16 state arrays stay in
// true VGPRs (round-1 compiled to 68 VGPR + AGPR spill => accvgpr ping-pong).
__global__ __launch_bounds__(BLOCK, 3) void ipm_knapsack_kernel(
        const float* __restrict__ costs,
        const float* __restrict__ weights,
        float* __restrict__ out) {
    __shared__ float lds[8];
    const int row = blockIdx.x;
    const int t   = threadIdx.x;

    float c[PER], w[PER], x[PER], g[PER], wih[PER], tinv[PER];

    const float4* c4 = reinterpret_cast<const float4*>(costs + (size_t)row * N_ELEM);
    const float4* w4 = reinterpret_cast<const float4*>(weights);
    #pragma unroll
    for (int k = 0; k < 4; ++k) {
        float4 cc = c4[t + 256 * k];
        float4 ww = w4[t + 256 * k];
        c[4*k+0] = -cc.x; c[4*k+1] = -cc.y; c[4*k+2] = -cc.z; c[4*k+3] = -cc.w;
        w[4*k+0] =  ww.x; w[4*k+1] =  ww.y; w[4*k+2] =  ww.z; w[4*k+3] =  ww.w;
    }

    // x0 = capacity / sum(weights); F2_0 = x0*sum(w) - capacity (~1 ulp of 0).
    float ws = 0.0f, zz = 0.0f;
    #pragma unroll
    for (int k = 0; k < PER; ++k) ws += w[k];
    block_reduce2(ws, zz, lds);
    const float x0 = CAPACITY / ws;
    #pragma unroll
    for (int k = 0; k < PER; ++k) x[k] = x0;
    float lam = 0.0f;
    // Newton equality-feasibility identity: sum(w*dx) = -F2, so after a step
    // of length alpha: F2 <- (1-alpha)*F2. Maintain analytically (drops s3).
    float f2 = fmaf(x0, ws, -CAPACITY);

    for (int it = 0; it <= NITER; ++it) {
        const float mu   = (it < 10) ? __uint_as_float((unsigned)(127 - it) << 23) : DAMPING;
        const float m2mu = -2.0f * mu;

        // ---- Phase A: residual/Hessian products + 2 row-sums ----
        // u = x(1-x); H = mu*(1-2u)/u^2; one rcp r = 1/(u*mu*(1-2u)) gives
        // 1/u = r*d and 1/H = u^3*r.
        float s1 = 0.0f, s2 = 0.0f;
        #pragma unroll
        for (int k = 0; k < PER; ++k) {
            const float xk = x[k], wk = w[k];
            const float p   = 1.0f - xk;
            const float u   = xk * p;
            const float d   = fmaf(m2mu, u, mu);          // mu*(1-2u) = mu*H*u^2/mu ... > 0
            const float r   = raw_rcp(u * d);
            const float ti  = r * d;                      // 1/u
            const float q   = fmaf(2.0f, xk, -1.0f);      // 2x-1
            const float f1  = fmaf(q, mu * ti, fmaf(lam, wk, c[k]));
            const float u2  = u * u;
            const float iH  = (u2 * u) * r;               // u^3 * r = 1/H
            const float gk  = f1 * iH;
            const float wi  = wk * iH;
            s1 = fmaf(wk, gk, s1);                        // sum (w/H)*F1
            s2 = fmaf(wk, wi, s2);                        // sum (w/H)*w
            g[k] = gk; wih[k] = wi; tinv[k] = ti;
        }
        block_reduce2(s1, s2, lds);
        const float dlam = (f2 - s1) * raw_rcp(s2);       // scalar Schur

        if (it == NITER) {
            // ---- KKT refine at mu=damping: out = x + dx = x - (g + dlam*wih)
            float4* o4 = reinterpret_cast<float4*>(out + (size_t)row * N_ELEM);
            #pragma unroll
            for (int k = 0; k < 4; ++k) {
                float4 v;
                v.x = x[4*k+0] - fmaf(dlam, wih[4*k+0], g[4*k+0]);
                v.y = x[4*k+1] - fmaf(dlam, wih[4*k+1], g[4*k+1]);
                v.z = x[4*k+2] - fmaf(dlam, wih[4*k+2], g[4*k+2]);
                v.w = x[4*k+3] - fmaf(dlam, wih[4*k+3], g[4*k+3]);
                o4[t + 256 * k] = v;
            }
            return;
        }

        // ---- Phase B: division-free fraction-to-boundary ----
        // dxn = -dx = g + dlam*wih.  min_k t_k == 1/max_k m_k with
        // m = max( dx/(1-x), -dx/x ) = max( -dxn*(x/u), dxn*(1/u - x/u) ).
        float m = 0.0f;
        #pragma unroll
        for (int k = 0; k < PER; ++k) {
            const float dxn = fmaf(dlam, wih[k], g[k]);
            const float ti  = tinv[k];
            const float xt  = x[k] * ti;                  // 1/(1-x)
            const float pt  = ti - xt;                    // 1/x
            const float aa  = -dxn * xt;
            const float bb  =  dxn * pt;
            m = fmaxf(m, fmaxf(aa, bb));                  // v_max3
        }
        m = block_reduce_max(m, lds);
        const float alpha = fminf(1.0f, 0.99f * raw_rcp(m));  // m=0 -> inf -> 1

        #pragma unroll
        for (int k = 0; k < PER; ++k) {
            const float dxn = fmaf(dlam, wih[k], g[k]);
            x[k] = fmaf(-alpha, dxn, x[k]);
        }
        lam = fmaf(alpha, dlam, lam);
        f2  = fmaf(-alpha, f2, f2);                       // F2 *= (1-alpha)
    }
}

extern "C" void kernel_launch(void* const* d_in, const int* in_sizes, int n_in,
                              void* d_out, int out_size, void* d_ws, size_t ws_size,
                              hipStream_t stream) {
    const float* costs   = (const float*)d_in[0];
    const float* weights = (const float*)d_in[1];
    float* out = (float*)d_out;
    const int B = in_sizes[0] / N_ELEM;   // 2048 rows
    ipm_knapsack_kernel<<<B, BLOCK, 0, stream>>>(costs, weights, out);
}